// Round 8
// baseline (80.520 us; speedup 1.0000x reference)
//
#include <hip/hip_runtime.h>
#include <math.h>

#define BATCH    32
#define NHEADS   32
#define KVHEADS  8
#define GRP      4
#define HSZ      128
#define BLKSZ    16
#define BPS      128
#define NTHREADS 256              // 4 waves
#define CHUNK    64               // tokens per split (4 cache blocks)
#define NSPLIT   32               // 2048 / CHUNK
#define SCALE    0.08838834764831843f   // 1/sqrt(128)

#define NPART    ((size_t)BATCH * KVHEADS * GRP * NSPLIT)     // 32768

__device__ __forceinline__ void dot4(float4& acc, const float* qb, const float4 k) {
    const float4 qa = *(const float4*)(qb);
    const float4 qg = *(const float4*)(qb + HSZ);
    const float4 qc = *(const float4*)(qb + 2 * HSZ);
    const float4 qd = *(const float4*)(qb + 3 * HSZ);
    acc.x = fmaf(qa.x,k.x,fmaf(qa.y,k.y,fmaf(qa.z,k.z,fmaf(qa.w,k.w,acc.x))));
    acc.y = fmaf(qg.x,k.x,fmaf(qg.y,k.y,fmaf(qg.z,k.z,fmaf(qg.w,k.w,acc.y))));
    acc.z = fmaf(qc.x,k.x,fmaf(qc.y,k.y,fmaf(qc.z,k.z,fmaf(qc.w,k.w,acc.z))));
    acc.w = fmaf(qd.x,k.x,fmaf(qd.y,k.y,fmaf(qd.z,k.z,fmaf(qd.w,k.w,acc.w))));
}

__device__ __forceinline__ void red2(float4& a) {
    a.x += __shfl_xor(a.x,1); a.x += __shfl_xor(a.x,2);
    a.y += __shfl_xor(a.y,1); a.y += __shfl_xor(a.y,2);
    a.z += __shfl_xor(a.z,1); a.z += __shfl_xor(a.z,2);
    a.w += __shfl_xor(a.w,1); a.w += __shfl_xor(a.w,2);
}

// ---------------- split kernel: one WG per (b, kvh, chunk64); wave = K/V tile, then head ----------------
__global__ __launch_bounds__(NTHREADS, 4) void pa_partial(
    const float* __restrict__ query,
    const float* __restrict__ k_new,
    const float* __restrict__ v_new,
    const float* __restrict__ k_cache,
    const float* __restrict__ v_cache,
    const int*  __restrict__ block_tables,
    const int*  __restrict__ ctx_lens,
    float* __restrict__ pm, float* __restrict__ pl, float* __restrict__ po)
{
    const int chunk = blockIdx.x & (NSPLIT - 1);
    const int kvh   = (blockIdx.x >> 5) & (KVHEADS - 1);
    const int b     = blockIdx.x >> 8;
    const int ctx   = ctx_lens[b];
    const int t0    = chunk * CHUNK;
    if (t0 > ctx) return;                        // inactive split

    const int tid  = threadIdx.x;
    const int lane = tid & 63;
    const int w    = tid >> 6;                   // wave id

    __shared__ float q_s[GRP][HSZ];              // roped * SCALE
    __shared__ float kn_s[HSZ];                  // roped k_new
    __shared__ float vt[CHUNK][HSZ + 4];         // V tile, +4 pad kills 16-way bank conflict
    __shared__ float sp[CHUNK][GRP];             // scores -> probs
    __shared__ int   bt_s[CHUNK / BLKSZ];        // 4

    // ---- stage: RoPE(pos=ctx+1) q (pre-scaled) + k_new; block table ----
    {
        const int   i    = tid & 63;
        const float p    = (float)(ctx + 1);
        const float invf = exp2f(-((float)i / 64.0f) * 13.287712379549449f); // 10000^(-2i/128)
        float s_, c_;
        sincosf(p * invf, &s_, &c_);
        const int g = tid >> 6;
        const float* qp = query + ((size_t)b * NHEADS + kvh * GRP + g) * HSZ;
        const float x1 = qp[i], x2 = qp[i + 64];
        q_s[g][i]      = (x1 * c_ - x2 * s_) * SCALE;
        q_s[g][i + 64] = (x2 * c_ + x1 * s_) * SCALE;
        if (tid < 64) {
            const float* kp = k_new + ((size_t)b * KVHEADS + kvh) * HSZ;
            const float y1 = kp[i], y2 = kp[i + 64];
            kn_s[i]      = y1 * c_ - y2 * s_;
            kn_s[i + 64] = y2 * c_ + y1 * s_;
        }
        if (tid < CHUNK / BLKSZ) bt_s[tid] = block_tables[b * BPS + chunk * (CHUNK / BLKSZ) + tid];
    }
    __syncthreads();

    const int  nvalid  = min(CHUNK, ctx - t0 + 1);   // valid rows incl. newest
    const bool has_new = (chunk == (ctx >> 6));
    const int  tc      = ctx - t0;                   // newest row index if has_new

    const int rg = lane >> 2;            // row within this wave's 16-token tile
    const int j  = lane & 3;             // dim-slice lane
    const int jo = j << 2;
    const int t  = w * 16 + rg;          // token row in chunk (wave w owns tile w)
    const int tcl = min(t, nvalid - 1);  // clamped row (defined data for invalid rows)

    // ---- phase 1: K+V loads together (one exposure), scores, V -> LDS ----
    {
        const size_t rowbase = (((size_t)bt_s[tcl >> 4] * BLKSZ + (tcl & 15)) * KVHEADS + kvh) * (size_t)HSZ;
        const float* kr = k_cache + rowbase + jo;
        const float* vr = (has_new && tcl == tc)
                        ? (v_new + ((size_t)b * KVHEADS + kvh) * HSZ + jo)
                        : (v_cache + rowbase + jo);
        float4 ka[8], va[8];
#pragma unroll
        for (int u = 0; u < 8; ++u) ka[u] = *(const float4*)(kr + u * 16);
#pragma unroll
        for (int u = 0; u < 8; ++u) va[u] = *(const float4*)(vr + u * 16);

        float4 acc = make_float4(0.f, 0.f, 0.f, 0.f);
#pragma unroll
        for (int u = 0; u < 8; ++u) dot4(acc, &q_s[0][u * 16 + jo], ka[u]);
        red2(acc);
        if (j == 0 && t < nvalid) *(float4*)&sp[t][0] = acc;

#pragma unroll
        for (int u = 0; u < 8; ++u) *(float4*)&vt[t][u * 16 + jo] = va[u];
    }
    // newest token: overwrite its score from roped k_new (same wave that owns the row)
    if (has_new && w == (tc >> 4) && rg == (tc & 15)) {
        float4 acc = make_float4(0.f, 0.f, 0.f, 0.f);
#pragma unroll
        for (int u = 0; u < 8; ++u) dot4(acc, &q_s[0][u * 16 + jo], *(const float4*)&kn_s[u * 16 + jo]);
        red2(acc);
        if (j == 0) *(float4*)&sp[tc][0] = acc;
    }
    __syncthreads();

    // ---- phase 2: softmax over 64 tokens; thread (t=lane, g=wave) ----
    {
        const int tt = lane;
        float sc = sp[tt][w];
        if (tt >= nvalid) sc = -INFINITY;
        float mx = sc;
#pragma unroll
        for (int hop = 1; hop <= 32; hop <<= 1) mx = fmaxf(mx, __shfl_xor(mx, hop));
        const float pr = __expf(sc - mx);
        float ls = pr;
#pragma unroll
        for (int hop = 1; hop <= 32; hop <<= 1) ls += __shfl_xor(ls, hop);
        sp[tt][w] = pr;                       // 0 for invalid rows
        if (lane == 0) {
            const size_t idx = (((size_t)(b * KVHEADS + kvh)) * GRP + w) * NSPLIT + chunk;
            pm[idx] = mx; pl[idx] = ls;
        }
    }
    __syncthreads();

    // ---- phase 3: PV from LDS only (wave = head); no merge, no global stalls ----
    {
        const int d0 = lane << 1;                 // 2 dims per lane
        float2 oe = make_float2(0.f, 0.f), oo = make_float2(0.f, 0.f);
#pragma unroll 8
        for (int tt = 0; tt + 1 < nvalid; tt += 2) {
            const float p0 = sp[tt][w];
            const float p1 = sp[tt + 1][w];
            const float2 v0 = *(const float2*)&vt[tt][d0];
            const float2 v1 = *(const float2*)&vt[tt + 1][d0];
            oe.x = fmaf(p0, v0.x, oe.x); oe.y = fmaf(p0, v0.y, oe.y);
            oo.x = fmaf(p1, v1.x, oo.x); oo.y = fmaf(p1, v1.y, oo.y);
        }
        if (nvalid & 1) {
            const int tt = nvalid - 1;
            const float p0 = sp[tt][w];
            const float2 v0 = *(const float2*)&vt[tt][d0];
            oe.x = fmaf(p0, v0.x, oe.x); oe.y = fmaf(p0, v0.y, oe.y);
        }
        const size_t idx = (((size_t)(b * KVHEADS + kvh)) * GRP + w) * NSPLIT + chunk;
        float2 o = make_float2(oe.x + oo.x, oe.y + oo.y);
        *(float2*)&po[idx * HSZ + d0] = o;
    }
}

// ---------------- reduce kernel: one WG per (b, kvh) ----------------
__global__ __launch_bounds__(512) void pa_reduce(
    const int*  __restrict__ ctx_lens,
    const float* __restrict__ pm, const float* __restrict__ pl,
    const float* __restrict__ po, float* __restrict__ out)
{
    const int b    = blockIdx.x >> 3;
    const int kvh  = blockIdx.x & 7;
    const int ctx  = ctx_lens[b];
    const int nact = (ctx >> 6) + 1;
    const int tid  = threadIdx.x;
    const int g    = tid >> 7;
    const int d    = tid & 127;
    const size_t idx = (((size_t)(b * KVHEADS + kvh)) * GRP + g) * NSPLIT;

    float M = -INFINITY;
    for (int p = 0; p < nact; ++p) M = fmaxf(M, pm[idx + p]);
    float L = 0.f, O = 0.f;
    for (int p = 0; p < nact; ++p) {
        const float w = __expf(pm[idx + p] - M);
        L += pl[idx + p] * w;
        O += po[(idx + p) * HSZ + d] * w;
    }
    out[((size_t)b * NHEADS + kvh * GRP + g) * HSZ + d] = O / L;
}

// ---------------- fallback: single kernel (if ws too small) ----------------
__device__ __forceinline__ float hsum32(float v) {
    v += __shfl_xor(v, 1); v += __shfl_xor(v, 2); v += __shfl_xor(v, 4);
    v += __shfl_xor(v, 8); v += __shfl_xor(v, 16);
    return v;
}
__device__ __forceinline__ void proc_row_f(const float4 kv, const float4 vv,
                                           const float4* qf, float* m, float* l, float4* o) {
    float s[GRP];
#pragma unroll
    for (int g = 0; g < GRP; ++g)
        s[g] = qf[g].x*kv.x + qf[g].y*kv.y + qf[g].z*kv.z + qf[g].w*kv.w;
#pragma unroll
    for (int g = 0; g < GRP; ++g) s[g] = hsum32(s[g]);
#pragma unroll
    for (int g = 0; g < GRP; ++g) {
        const float sc = s[g] * SCALE;
        const float mn = fmaxf(m[g], sc);
        const float cf = __expf(m[g] - mn);
        const float pp = __expf(sc - mn);
        l[g] = l[g] * cf + pp;
        o[g].x = o[g].x*cf + pp*vv.x; o[g].y = o[g].y*cf + pp*vv.y;
        o[g].z = o[g].z*cf + pp*vv.z; o[g].w = o[g].w*cf + pp*vv.w;
        m[g] = mn;
    }
}
__global__ __launch_bounds__(512) void paged_attn_single(
    const float* __restrict__ query, const float* __restrict__ k_new,
    const float* __restrict__ v_new, const float* __restrict__ k_cache,
    const float* __restrict__ v_cache, const int* __restrict__ block_tables,
    const int* __restrict__ ctx_lens, float* __restrict__ out)
{
    const int wg = blockIdx.x, b = wg >> 3, kvh = wg & 7;
    const int tid = threadIdx.x, sub = tid & 31, proc = tid >> 5;
    const int ctx = ctx_lens[b];
    __shared__ float q_s[GRP][HSZ];
    __shared__ float kn_s[HSZ];
    __shared__ int   bt_s[BPS];
    __shared__ float m_s[16][GRP];
    __shared__ float l_s[16][GRP];
    __shared__ float o_s[16][GRP][HSZ];
    {
        const float p = (float)(ctx + 1);
        if (tid < 320) {
            const int   i    = tid & 63;
            const float invf = exp2f(-((float)i / 64.0f) * 13.287712379549449f);
            float s_, c_;
            sincosf(p * invf, &s_, &c_);
            if (tid < 256) {
                const int g = tid >> 6;
                const float* qp = query + ((size_t)b * NHEADS + kvh * GRP + g) * HSZ;
                const float x1 = qp[i], x2 = qp[i + 64];
                q_s[g][i] = x1*c_ - x2*s_; q_s[g][i+64] = x2*c_ + x1*s_;
            } else {
                const float* kp = k_new + ((size_t)b * KVHEADS + kvh) * HSZ;
                const float x1 = kp[i], x2 = kp[i + 64];
                kn_s[i] = x1*c_ - x2*s_; kn_s[i+64] = x2*c_ + x1*s_;
            }
        } else if (tid < 448) {
            bt_s[tid - 320] = block_tables[b * BPS + (tid - 320)];
        }
    }
    __syncthreads();
    const int d0 = sub << 2;
    float4 qf[GRP];
#pragma unroll
    for (int g = 0; g < GRP; ++g) qf[g] = *(const float4*)&q_s[g][d0];
    float m[GRP], l[GRP]; float4 o[GRP];
#pragma unroll
    for (int g = 0; g < GRP; ++g) { m[g] = -INFINITY; l[g] = 0.f; o[g] = make_float4(0,0,0,0); }
    for (int t = proc; t < ctx; t += 16) {
        const int blk = bt_s[t >> 4];
        const size_t a0 = (((size_t)blk*BLKSZ + (t & 15))*KVHEADS + kvh)*HSZ + d0;
        proc_row_f(*(const float4*)(k_cache + a0), *(const float4*)(v_cache + a0), qf, m, l, o);
    }
    if (proc == (ctx & 15)) {
        proc_row_f(*(const float4*)&kn_s[d0],
                   *(const float4*)(v_new + ((size_t)b*KVHEADS + kvh)*HSZ + d0), qf, m, l, o);
    }
    if (sub == 0) {
#pragma unroll
        for (int g = 0; g < GRP; ++g) { m_s[proc][g] = m[g]; l_s[proc][g] = l[g]; }
    }
#pragma unroll
    for (int g = 0; g < GRP; ++g) *(float4*)&o_s[proc][g][d0] = o[g];
    __syncthreads();
    {
        const int g = tid >> 7, d = tid & 127;
        float mt = -INFINITY;
#pragma unroll
        for (int p = 0; p < 16; ++p) mt = fmaxf(mt, m_s[p][g]);
        float lt = 0.f, ot = 0.f;
#pragma unroll
        for (int p = 0; p < 16; ++p) {
            const float wgt = __expf(m_s[p][g] - mt);
            lt += l_s[p][g]*wgt; ot += o_s[p][g][d]*wgt;
        }
        out[((size_t)b*NHEADS + kvh*GRP + g)*HSZ + d] = ot / lt;
    }
}

extern "C" void kernel_launch(void* const* d_in, const int* in_sizes, int n_in,
                              void* d_out, int out_size, void* d_ws, size_t ws_size,
                              hipStream_t stream) {
    const float* query        = (const float*)d_in[0];
    const float* k_new        = (const float*)d_in[1];
    const float* v_new        = (const float*)d_in[2];
    const float* k_cache      = (const float*)d_in[3];
    const float* v_cache      = (const float*)d_in[4];
    const int*   block_tables = (const int*)d_in[5];
    const int*   ctx_lens     = (const int*)d_in[6];
    float*       out          = (float*)d_out;

    const size_t need = (NPART * 2 + NPART * HSZ) * sizeof(float);  // ~17 MB

    if (ws_size >= need) {
        float* pm = (float*)d_ws;
        float* pl = pm + NPART;
        float* po = pl + NPART;
        pa_partial<<<dim3(BATCH * KVHEADS * NSPLIT), dim3(NTHREADS), 0, stream>>>(
            query, k_new, v_new, k_cache, v_cache, block_tables, ctx_lens, pm, pl, po);
        pa_reduce<<<dim3(BATCH * KVHEADS), dim3(512), 0, stream>>>(
            ctx_lens, pm, pl, po, out);
    } else {
        paged_attn_single<<<dim3(BATCH * KVHEADS), dim3(512), 0, stream>>>(
            query, k_new, v_new, k_cache, v_cache, block_tables, ctx_lens, out);
    }
}